// Round 8
// baseline (944.911 us; speedup 1.0000x reference)
//
#include <hip/hip_runtime.h>

// APPNP propagation: h <- (1-alpha) * A @ h + alpha * x, K=10 steps.
// R5: unroll x8 + bf16 xb -> 967.6. R6: padded CSR -> 885.7. R7: col sort
//     FAILED (909.7). R8: sort removed + unroll x16 -> 864.6 (BEST).
// R10: bucketed build -> REGRESSED (940.5): bucket_to_csr grid=64 is 1
//     wave/CU, latency-exposed. Reverted. KEY spmm counters from R10:
//     FETCH 280 MB/step (L2 captures ~1/3; old 425 was nt-inflated),
//     VALUBusy 40%, occ 73%, VGPR=32 -> compiler capped in-flight gathers
//     at ~8 (x16 unroll never materialized); VALU floor ~39us, mem floor
//     ~44us, actual ~73-83 -> ~35us/step exposed latency (csr chunk load ->
//     gather address serial dependency, ~200cyc L2 per chunk).
// R11: (a) build reverted to R8 scatter_padded; (b) spmm software-pipelined:
//     csr chunk double-buffered in regs, prefetch chunk k+1 between issuing
//     chunk k's gathers and consuming them; float2 accumulators (pk_fma).

#define N_NODES 100000
#define N_EDGES 1600000
#define D_FEAT  128
#define ALPHA   0.1f
#define K_STEPS 10
#define MAXDEG  64   // P(Poisson(16) >= 64) ~ 1e-19; guarded anyway

#define SCAN_ELEMS 512
#define SCAN_NBLK  ((N_NODES + SCAN_ELEMS - 1) / SCAN_ELEMS)  // 196

static __device__ __forceinline__ float bf2f(unsigned u16) {
    return __uint_as_float(u16 << 16);
}
static __device__ __forceinline__ unsigned f2bf(float f) {
    unsigned u = __float_as_uint(f);
    return (u + 0x7fffu + ((u >> 16) & 1u)) >> 16;  // round-to-nearest-even
}

// ---------- padded CSR build: one atomic pass (R8 version) ----------

__global__ __launch_bounds__(256) void scatter_padded(const int* __restrict__ rows,
                                                      const int* __restrict__ cols,
                                                      const float* __restrict__ w,
                                                      int* __restrict__ cnt,
                                                      int2* __restrict__ csrp) {
    int e = blockIdx.x * 256 + threadIdx.x;
    if (e < N_EDGES) {
        int r = rows[e];
        int pos = atomicAdd(&cnt[r], 1);
        if (pos < MAXDEG) {
            int2 cw;
            cw.x = cols[e];
            cw.y = __float_as_int((1.0f - ALPHA) * w[e]);  // fold 0.9 into weight
            csrp[((size_t)r << 6) + pos] = cw;
        }
    }
}

// ---------- compact CSR build (fallback tier, R5 path) ----------

__global__ __launch_bounds__(256) void hist_kernel(const int* __restrict__ rows,
                                                   int* __restrict__ deg) {
    int e = blockIdx.x * 256 + threadIdx.x;
    if (e < N_EDGES) atomicAdd(&deg[rows[e]], 1);
}

__global__ __launch_bounds__(256) void scan_partial(const int* __restrict__ deg,
                                                    int* __restrict__ partial) {
    __shared__ int s[256];
    int b = blockIdx.x, t = threadIdx.x;
    int i0 = b * SCAN_ELEMS + t * 2;
    int v0 = (i0 < N_NODES) ? deg[i0] : 0;
    int v1 = (i0 + 1 < N_NODES) ? deg[i0 + 1] : 0;
    s[t] = v0 + v1;
    __syncthreads();
    for (int off = 128; off > 0; off >>= 1) {
        if (t < off) s[t] += s[t + off];
        __syncthreads();
    }
    if (t == 0) partial[b] = s[0];
}

__global__ __launch_bounds__(256) void scan_top(int* __restrict__ partial) {
    __shared__ int s[256];
    int t = threadIdx.x;
    s[t] = (t < SCAN_NBLK) ? partial[t] : 0;
    __syncthreads();
    for (int off = 1; off < 256; off <<= 1) {
        int v = (t >= off) ? s[t - off] : 0;
        __syncthreads();
        s[t] += v;
        __syncthreads();
    }
    if (t < SCAN_NBLK) partial[t] = (t == 0) ? 0 : s[t - 1];
}

__global__ __launch_bounds__(256) void scan_final(int* __restrict__ deg_cursor,
                                                  const int* __restrict__ partial,
                                                  int* __restrict__ row_ptr) {
    __shared__ int s[256];
    int b = blockIdx.x, t = threadIdx.x;
    int i0 = b * SCAN_ELEMS + t * 2;
    int v0 = (i0 < N_NODES) ? deg_cursor[i0] : 0;
    int v1 = (i0 + 1 < N_NODES) ? deg_cursor[i0 + 1] : 0;
    int pair = v0 + v1;
    s[t] = pair;
    __syncthreads();
    for (int off = 1; off < 256; off <<= 1) {
        int v = (t >= off) ? s[t - off] : 0;
        __syncthreads();
        s[t] += v;
        __syncthreads();
    }
    int ex = partial[b] + s[t] - pair;  // exclusive prefix of element 2t
    if (i0 < N_NODES)     { row_ptr[i0] = ex;          deg_cursor[i0] = ex; }
    if (i0 + 1 < N_NODES) { row_ptr[i0 + 1] = ex + v0; deg_cursor[i0 + 1] = ex + v0; }
    if (b == 0 && t == 0) row_ptr[N_NODES] = N_EDGES;
}

__global__ __launch_bounds__(256) void scatter_kernel(const int* __restrict__ rows,
                                                      const int* __restrict__ cols,
                                                      const float* __restrict__ w,
                                                      int* __restrict__ cursor,
                                                      int2* __restrict__ csr) {
    int e = blockIdx.x * 256 + threadIdx.x;
    if (e < N_EDGES) {
        int pos = atomicAdd(&cursor[rows[e]], 1);
        int2 cw;
        cw.x = cols[e];
        cw.y = __float_as_int((1.0f - ALPHA) * w[e]);  // fold 0.9 into the weight
        csr[pos] = cw;
    }
}

// x fp32 -> packed 2xbf16 per u32 (row-major, 64 u32 per row)
__global__ __launch_bounds__(256) void x_to_bf16(const float2* __restrict__ x2,
                                                 unsigned* __restrict__ xb, int n) {
    int i = blockIdx.x * 256 + threadIdx.x;
    if (i < n) {
        float2 v = x2[i];
        xb[i] = f2bf(v.x) | (f2bf(v.y) << 16);
    }
}

// ---------- propagation step: one wave per row ----------
// SRC_BF/DST_BF: gather src / dst format. X_BF: alpha*x term source format.
// PAD: padded CSR (rp = cnt[], edges at row*64) vs compact (rp = row_ptr[]).

template <bool SRC_BF, bool DST_BF, bool X_BF, bool PAD>
__global__ __launch_bounds__(256) void row_spmm_t(const int* __restrict__ rp,
                                                  const int2* __restrict__ csr,
                                                  const void* __restrict__ xsrc,
                                                  const void* __restrict__ src,
                                                  void* __restrict__ dst) {
    int row = (blockIdx.x * 256 + threadIdx.x) >> 6;
    int lane = threadIdx.x & 63;
    if (row >= N_NODES) return;
    int beg, end;
    if (PAD) {
        int cn = rp[row];
        cn = (cn < MAXDEG) ? cn : MAXDEG;
        beg = row << 6;
        end = beg + cn;
    } else {
        beg = rp[row];
        end = rp[row + 1];
    }

    // x-term: issued early, overlaps the gather chain.
    float xtx, xty;
    if (X_BF) {
        unsigned u = ((const unsigned*)xsrc)[(size_t)row * 64 + lane];
        xtx = ALPHA * bf2f(u & 0xffffu);
        xty = ALPHA * bf2f(u >> 16);
    } else {
        float2 xv = ((const float2*)xsrc)[(size_t)row * 64 + lane];
        xtx = ALPHA * xv.x;
        xty = ALPHA * xv.y;
    }

    const float2*   sf = (const float2*)src;
    const unsigned* sb = (const unsigned*)src;

    float2 acc[4];
    #pragma unroll
    for (int u = 0; u < 4; ++u) { acc[u].x = 0.f; acc[u].y = 0.f; }

    auto gather = [&](int col) -> float2 {
        if (SRC_BF) {
            unsigned u = sb[(size_t)col * 64 + lane];
            float2 v;
            v.x = bf2f(u & 0xffffu);
            v.y = bf2f(u >> 16);
            return v;
        } else {
            return sf[(size_t)col * 64 + lane];
        }
    };

    int j = beg;
    // Software-pipelined x8: csr chunk double-buffered in registers.
    // Order per iteration: issue 8 gathers (addresses from current chunk) ->
    // prefetch next csr chunk (independent, hides under gathers) -> consume
    // gathers with packed FMAs. Breaks the csr-load -> gather-address serial
    // dependency that exposed ~200cyc L2 latency per chunk.
    if (end - j >= 8) {
        int2 cw[8];
        #pragma unroll
        for (int u = 0; u < 8; ++u) cw[u] = csr[j + u];
        for (;;) {
            float2 v[8];
            #pragma unroll
            for (int u = 0; u < 8; ++u) v[u] = gather(cw[u].x);
            j += 8;
            const bool more = (end - j >= 8);  // wave-uniform (beg/end per row)
            int2 cwn[8];
            if (more) {
                #pragma unroll
                for (int u = 0; u < 8; ++u) cwn[u] = csr[j + u];
            }
            #pragma unroll
            for (int u = 0; u < 8; ++u) {
                float wv = __int_as_float(cw[u].y);
                acc[u & 3].x += wv * v[u].x;
                acc[u & 3].y += wv * v[u].y;
            }
            if (!more) break;
            #pragma unroll
            for (int u = 0; u < 8; ++u) cw[u] = cwn[u];
        }
    }
    if (end - j >= 4) {
        int2 cw[4];
        #pragma unroll
        for (int u = 0; u < 4; ++u) cw[u] = csr[j + u];
        float2 v[4];
        #pragma unroll
        for (int u = 0; u < 4; ++u) v[u] = gather(cw[u].x);
        #pragma unroll
        for (int u = 0; u < 4; ++u) {
            float wv = __int_as_float(cw[u].y);
            acc[u].x += wv * v[u].x;
            acc[u].y += wv * v[u].y;
        }
        j += 4;
    }
    for (; j < end; ++j) {
        int2 cw = csr[j];
        float2 v = gather(cw.x);
        float wv = __int_as_float(cw.y);
        acc[0].x += wv * v.x;
        acc[0].y += wv * v.y;
    }

    float ox = xtx + (acc[0].x + acc[1].x) + (acc[2].x + acc[3].x);
    float oy = xty + (acc[0].y + acc[1].y) + (acc[2].y + acc[3].y);

    if (DST_BF) {
        ((unsigned*)dst)[(size_t)row * 64 + lane] = f2bf(ox) | (f2bf(oy) << 16);
    } else {
        float2 o; o.x = ox; o.y = oy;
        ((float2*)dst)[(size_t)row * 64 + lane] = o;
    }
}

// ---------- fallback (R0 atomic path) if ws too small ----------

__global__ __launch_bounds__(256) void init_step(const float4* __restrict__ x,
                                                 float4* __restrict__ dst, int n4) {
    int i = blockIdx.x * 256 + threadIdx.x;
    if (i < n4) {
        float4 v = x[i];
        dst[i] = make_float4(ALPHA * v.x, ALPHA * v.y, ALPHA * v.z, ALPHA * v.w);
    }
}

__global__ __launch_bounds__(256) void edge_scatter(const int* __restrict__ rows,
                                                    const int* __restrict__ cols,
                                                    const float* __restrict__ w,
                                                    const float* __restrict__ h,
                                                    float* __restrict__ dst) {
    unsigned t = blockIdx.x * 256u + threadIdx.x;
    unsigned e = t >> 5;
    unsigned l = t & 31u;
    if (e >= N_EDGES) return;
    int r = rows[e];
    int c = cols[e];
    float we = (1.0f - ALPHA) * w[e];
    const float4* hc = (const float4*)(h + (size_t)c * D_FEAT);
    float4 v = hc[l];
    float* dr = dst + (size_t)r * D_FEAT + (size_t)l * 4;
    unsafeAtomicAdd(dr + 0, we * v.x);
    unsafeAtomicAdd(dr + 1, we * v.y);
    unsafeAtomicAdd(dr + 2, we * v.z);
    unsafeAtomicAdd(dr + 3, we * v.w);
}

extern "C" void kernel_launch(void* const* d_in, const int* in_sizes, int n_in,
                              void* d_out, int out_size, void* d_ws, size_t ws_size,
                              hipStream_t stream) {
    const float* x  = (const float*)d_in[0];
    const int*   ei = (const int*)d_in[1];  // [2, E] flat: rows then cols
    const float* ev = (const float*)d_in[2];
    const int* rows = ei;
    const int* cols = ei + N_EDGES;
    float* out = (float*)d_out;

    auto align16 = [](size_t o) { return (o + 15) & ~(size_t)15; };

    // --- padded layout (tier 1): ha, hb, cnt, csrp(64 slots/row), xb ---
    size_t p_off = 0;
    size_t p_ha   = p_off; p_off = align16(p_off + (size_t)N_NODES * D_FEAT * 2);
    size_t p_hb   = p_off; p_off = align16(p_off + (size_t)N_NODES * D_FEAT * 2);
    size_t p_cnt  = p_off; p_off = align16(p_off + (size_t)N_NODES * 4);
    size_t p_csr  = p_off; p_off = align16(p_off + (size_t)N_NODES * MAXDEG * 8);
    size_t p_xb   = p_off; p_off = align16(p_off + (size_t)N_NODES * D_FEAT * 2);
    size_t need_pad = p_off;  // ~128.6 MB

    // --- compact layout (tiers 2/3): ha, hb, rowptr, cursor, partial, csr, [xb] ---
    size_t c_off = 0;
    size_t c_ha      = c_off; c_off = align16(c_off + (size_t)N_NODES * D_FEAT * 2);
    size_t c_hb      = c_off; c_off = align16(c_off + (size_t)N_NODES * D_FEAT * 2);
    size_t c_rowptr  = c_off; c_off = align16(c_off + (size_t)(N_NODES + 1) * 4);
    size_t c_cursor  = c_off; c_off = align16(c_off + (size_t)N_NODES * 4);
    size_t c_partial = c_off; c_off = align16(c_off + (size_t)SCAN_NBLK * 4);
    size_t c_csr     = c_off; c_off = align16(c_off + (size_t)N_EDGES * 8);
    size_t need_base = c_off;  // ~64.8 MB
    size_t c_xb      = c_off; c_off = align16(c_off + (size_t)N_NODES * D_FEAT * 2);
    size_t need_xb   = c_off;  // ~90.4 MB

    const int row_blocks = (N_NODES * 64 + 255) / 256;  // 25000 (1 wave/row)
    const float2* x2 = (const float2*)x;

    if (ws_size >= need_pad) {
        // ---- tier 1: padded CSR (R8 build), pipelined spmm ----
        char* ws = (char*)d_ws;
        void*     h_a  = (void*)(ws + p_ha);
        void*     h_b  = (void*)(ws + p_hb);
        int*      cnt  = (int*)(ws + p_cnt);
        int2*     csrp = (int2*)(ws + p_csr);
        unsigned* xb   = (unsigned*)(ws + p_xb);

        hipMemsetAsync(cnt, 0, (size_t)N_NODES * 4, stream);
        const int edge_blocks_1t = (N_EDGES + 255) / 256;  // 6250
        scatter_padded<<<edge_blocks_1t, 256, 0, stream>>>(rows, cols, ev, cnt, csrp);

        const int nxb = N_NODES * D_FEAT / 2;
        x_to_bf16<<<(nxb + 255) / 256, 256, 0, stream>>>(x2, xb, nxb);

        row_spmm_t<true, true, true, true><<<row_blocks, 256, 0, stream>>>(
            cnt, csrp, (const void*)xb, (const void*)xb, h_a);
        for (int k = 1; k <= 8; ++k) {
            const void* src = (k & 1) ? h_a : h_b;
            void* dst = (k & 1) ? h_b : h_a;
            row_spmm_t<true, true, true, true><<<row_blocks, 256, 0, stream>>>(
                cnt, csrp, (const void*)xb, src, dst);
        }
        row_spmm_t<true, false, false, true><<<row_blocks, 256, 0, stream>>>(
            cnt, csrp, (const void*)x2, (const void*)h_a, (void*)out);
    } else if (ws_size >= need_base) {
        // ---- tiers 2/3: compact CSR (R5 path) ----
        char* ws = (char*)d_ws;
        void*  h_a     = (void*)(ws + c_ha);
        void*  h_b     = (void*)(ws + c_hb);
        int*   row_ptr = (int*)(ws + c_rowptr);
        int*   cursor  = (int*)(ws + c_cursor);
        int*   partial = (int*)(ws + c_partial);
        int2*  csr     = (int2*)(ws + c_csr);
        unsigned* xb   = (unsigned*)(ws + c_xb);
        const bool has_xb = (ws_size >= need_xb);
        const int edge_blocks_1t = (N_EDGES + 255) / 256;  // 6250

        hipMemsetAsync(cursor, 0, (size_t)N_NODES * 4, stream);
        hist_kernel<<<edge_blocks_1t, 256, 0, stream>>>(rows, cursor);
        scan_partial<<<SCAN_NBLK, 256, 0, stream>>>(cursor, partial);
        scan_top<<<1, 256, 0, stream>>>(partial);
        scan_final<<<SCAN_NBLK, 256, 0, stream>>>(cursor, partial, row_ptr);
        scatter_kernel<<<edge_blocks_1t, 256, 0, stream>>>(rows, cols, ev, cursor, csr);

        if (has_xb) {
            const int nxb = N_NODES * D_FEAT / 2;
            x_to_bf16<<<(nxb + 255) / 256, 256, 0, stream>>>(x2, xb, nxb);
            row_spmm_t<true, true, true, false><<<row_blocks, 256, 0, stream>>>(
                row_ptr, csr, (const void*)xb, (const void*)xb, h_a);
            for (int k = 1; k <= 8; ++k) {
                const void* src = (k & 1) ? h_a : h_b;
                void* dst = (k & 1) ? h_b : h_a;
                row_spmm_t<true, true, true, false><<<row_blocks, 256, 0, stream>>>(
                    row_ptr, csr, (const void*)xb, src, dst);
            }
            row_spmm_t<true, false, false, false><<<row_blocks, 256, 0, stream>>>(
                row_ptr, csr, (const void*)x2, (const void*)h_a, (void*)out);
        } else {
            row_spmm_t<false, true, false, false><<<row_blocks, 256, 0, stream>>>(
                row_ptr, csr, (const void*)x2, (const void*)x, h_a);
            for (int k = 1; k <= 8; ++k) {
                const void* src = (k & 1) ? h_a : h_b;
                void* dst = (k & 1) ? h_b : h_a;
                row_spmm_t<true, true, false, false><<<row_blocks, 256, 0, stream>>>(
                    row_ptr, csr, (const void*)x2, src, dst);
            }
            row_spmm_t<true, false, false, false><<<row_blocks, 256, 0, stream>>>(
                row_ptr, csr, (const void*)x2, (const void*)h_a, (void*)out);
        }
    } else {
        // Fallback: R0 atomic path (needs only the 51.2 MB ping buffer)
        float* wsf = (float*)d_ws;
        const int n4 = N_NODES * D_FEAT / 4;
        const int init_blocks = (n4 + 255) / 256;
        const int edge_blocks = (N_EDGES * 32 + 255) / 256;
        for (int k = 0; k < K_STEPS; ++k) {
            const float* src = (k == 0) ? x : ((k & 1) ? wsf : out);
            float* dst = (k & 1) ? out : wsf;
            init_step<<<init_blocks, 256, 0, stream>>>((const float4*)x, (float4*)dst, n4);
            edge_scatter<<<edge_blocks, 256, 0, stream>>>(rows, cols, ev, src, dst);
        }
    }
}

// Round 10
// 804.335 us; speedup vs baseline: 1.1748x; 1.1748x over previous
//
#include <hip/hip_runtime.h>

// APPNP propagation: h <- (1-alpha) * A @ h + alpha * x, K=10 steps.
// R5: unroll x8 + bf16 xb -> 967.6. R6: padded CSR -> 885.7. R8: unroll x16
//     -> 864.6 (BEST). R10: bucketed build REGRESSED (940.5) -- bucket_to_csr
//     grid=64 = 1 block/4CUs latency-exposed; ALSO csrp base was 16B-not-64B
//     aligned (rows straddled 3 lines, spmm 72.5->83us). R11: sw-pipelined
//     spmm REGRESSED (944.9): for(;;)+branch+16 v_movs/chunk beat the
//     compiler's own schedule. spmm is THROUGHPUT-capped (~3.8 TB/s fabric,
//     280MB/step); fp8 blocked (outputs ~6.5e4 overflow e4m3/e5m2).
// R12: spmm reverted to R8-exact. Build: bucketed v2 -- bucket_to_csr grid
//     = NBUCK (196, 1 bucket/block), all ws chunks 512B-aligned, tier-1
//     order ha,hb,xb,cnt,csrp so gbuf aliases contiguous hb+xb.
//     Pass A: per-block LDS hist -> 1 global atomic/(block,bucket); writes
//     contiguous ~167B runs per bucket -> L2 line-merge. Pass B: LDS
//     row-cursors (no global atomics); csrp stores confined to 256KB
//     window/bucket -> L2-resident full-line evictions.
// R13: resubmission of R12 unchanged (bench infra failed twice; 3rd infra
//     failure this session -- R0/R6 both cleared on identical resubmit).

#define N_NODES 100000
#define N_EDGES 1600000
#define D_FEAT  128
#define ALPHA   0.1f
#define K_STEPS 10
#define MAXDEG  64   // P(Poisson(16) >= 64) ~ 1e-19; guarded anyway

#define NBUCK 196    // buckets of 512 rows: (N_NODES + 511) >> 9
#define BCAP  16000  // entries/bucket; mean 8192, cap ~ +86 sigma
#define EPB_A 2048   // edges per block in pass A

#define SCAN_ELEMS 512
#define SCAN_NBLK  ((N_NODES + SCAN_ELEMS - 1) / SCAN_ELEMS)  // 196

static __device__ __forceinline__ float bf2f(unsigned u16) {
    return __uint_as_float(u16 << 16);
}
static __device__ __forceinline__ unsigned f2bf(float f) {
    unsigned u = __float_as_uint(f);
    return (u + 0x7fffu + ((u >> 16) & 1u)) >> 16;  // round-to-nearest-even
}

// ---------- bucketed CSR build (tier 1) ----------

__global__ __launch_bounds__(256) void bucket_scatter(const int* __restrict__ rows,
                                                      const int* __restrict__ cols,
                                                      const float* __restrict__ w,
                                                      int* __restrict__ gcount,
                                                      int4* __restrict__ gbuf) {
    __shared__ int h_cnt[NBUCK];
    __shared__ int h_base[NBUCK];
    __shared__ int h_cur[NBUCK];
    const int tid = threadIdx.x;
    for (int i = tid; i < NBUCK; i += 256) { h_cnt[i] = 0; h_cur[i] = 0; }
    __syncthreads();

    const int base_e = blockIdx.x * EPB_A + tid;
    int er[8]; int ec[8]; float ew[8];
    #pragma unroll
    for (int k = 0; k < 8; ++k) {
        int e = base_e + k * 256;
        bool v = (e < N_EDGES);
        er[k] = v ? rows[e] : -1;
        ec[k] = v ? cols[e] : 0;
        ew[k] = v ? w[e] : 0.f;
        if (v) atomicAdd(&h_cnt[er[k] >> 9], 1);
    }
    __syncthreads();
    for (int i = tid; i < NBUCK; i += 256) {
        h_base[i] = (h_cnt[i] > 0) ? atomicAdd(&gcount[i], h_cnt[i]) : 0;
    }
    __syncthreads();
    #pragma unroll
    for (int k = 0; k < 8; ++k) {
        if (er[k] >= 0) {
            int b = er[k] >> 9;
            int p = h_base[b] + atomicAdd(&h_cur[b], 1);
            if (p < BCAP) {
                int4 ent;
                ent.x = er[k];
                ent.y = ec[k];
                ent.z = __float_as_int((1.0f - ALPHA) * ew[k]);  // fold 0.9
                ent.w = 0;
                gbuf[(size_t)b * BCAP + p] = ent;
            }
        }
    }
}

__global__ __launch_bounds__(256) void bucket_to_csr(const int* __restrict__ gcount,
                                                     const int4* __restrict__ gbuf,
                                                     int* __restrict__ cnt,
                                                     int2* __restrict__ csrp) {
    __shared__ int rcur[512];
    const int tid = threadIdx.x;
    const int b = blockIdx.x;  // grid == NBUCK: one bucket per block
    for (int i = tid; i < 512; i += 256) rcur[i] = 0;
    __syncthreads();
    int n = gcount[b];
    if (n > BCAP) n = BCAP;
    for (int i = tid; i < n; i += 256) {
        int4 e = gbuf[(size_t)b * BCAP + i];
        int p = atomicAdd(&rcur[e.x & 511], 1);  // LDS atomic: position
        if (p < MAXDEG) {
            int2 cw;
            cw.x = e.y;
            cw.y = e.z;
            csrp[((size_t)e.x << 6) + p] = cw;
        }
    }
    __syncthreads();
    const int rowbase = b << 9;
    for (int i = tid; i < 512; i += 256) {
        int row = rowbase + i;
        if (row < N_NODES) cnt[row] = rcur[i];  // spmm clamps to MAXDEG
    }
}

// ---------- compact CSR build (fallback tier, R5 path) ----------

__global__ __launch_bounds__(256) void hist_kernel(const int* __restrict__ rows,
                                                   int* __restrict__ deg) {
    int e = blockIdx.x * 256 + threadIdx.x;
    if (e < N_EDGES) atomicAdd(&deg[rows[e]], 1);
}

__global__ __launch_bounds__(256) void scan_partial(const int* __restrict__ deg,
                                                    int* __restrict__ partial) {
    __shared__ int s[256];
    int b = blockIdx.x, t = threadIdx.x;
    int i0 = b * SCAN_ELEMS + t * 2;
    int v0 = (i0 < N_NODES) ? deg[i0] : 0;
    int v1 = (i0 + 1 < N_NODES) ? deg[i0 + 1] : 0;
    s[t] = v0 + v1;
    __syncthreads();
    for (int off = 128; off > 0; off >>= 1) {
        if (t < off) s[t] += s[t + off];
        __syncthreads();
    }
    if (t == 0) partial[b] = s[0];
}

__global__ __launch_bounds__(256) void scan_top(int* __restrict__ partial) {
    __shared__ int s[256];
    int t = threadIdx.x;
    s[t] = (t < SCAN_NBLK) ? partial[t] : 0;
    __syncthreads();
    for (int off = 1; off < 256; off <<= 1) {
        int v = (t >= off) ? s[t - off] : 0;
        __syncthreads();
        s[t] += v;
        __syncthreads();
    }
    if (t < SCAN_NBLK) partial[t] = (t == 0) ? 0 : s[t - 1];
}

__global__ __launch_bounds__(256) void scan_final(int* __restrict__ deg_cursor,
                                                  const int* __restrict__ partial,
                                                  int* __restrict__ row_ptr) {
    __shared__ int s[256];
    int b = blockIdx.x, t = threadIdx.x;
    int i0 = b * SCAN_ELEMS + t * 2;
    int v0 = (i0 < N_NODES) ? deg_cursor[i0] : 0;
    int v1 = (i0 + 1 < N_NODES) ? deg_cursor[i0 + 1] : 0;
    int pair = v0 + v1;
    s[t] = pair;
    __syncthreads();
    for (int off = 1; off < 256; off <<= 1) {
        int v = (t >= off) ? s[t - off] : 0;
        __syncthreads();
        s[t] += v;
        __syncthreads();
    }
    int ex = partial[b] + s[t] - pair;  // exclusive prefix of element 2t
    if (i0 < N_NODES)     { row_ptr[i0] = ex;          deg_cursor[i0] = ex; }
    if (i0 + 1 < N_NODES) { row_ptr[i0 + 1] = ex + v0; deg_cursor[i0 + 1] = ex + v0; }
    if (b == 0 && t == 0) row_ptr[N_NODES] = N_EDGES;
}

__global__ __launch_bounds__(256) void scatter_kernel(const int* __restrict__ rows,
                                                      const int* __restrict__ cols,
                                                      const float* __restrict__ w,
                                                      int* __restrict__ cursor,
                                                      int2* __restrict__ csr) {
    int e = blockIdx.x * 256 + threadIdx.x;
    if (e < N_EDGES) {
        int pos = atomicAdd(&cursor[rows[e]], 1);
        int2 cw;
        cw.x = cols[e];
        cw.y = __float_as_int((1.0f - ALPHA) * w[e]);  // fold 0.9 into the weight
        csr[pos] = cw;
    }
}

// x fp32 -> packed 2xbf16 per u32 (row-major, 64 u32 per row)
__global__ __launch_bounds__(256) void x_to_bf16(const float2* __restrict__ x2,
                                                 unsigned* __restrict__ xb, int n) {
    int i = blockIdx.x * 256 + threadIdx.x;
    if (i < n) {
        float2 v = x2[i];
        xb[i] = f2bf(v.x) | (f2bf(v.y) << 16);
    }
}

// ---------- propagation step: one wave per row (R8-exact) ----------
// SRC_BF/DST_BF: gather src / dst format. X_BF: alpha*x term source format.
// PAD: padded CSR (rp = cnt[], edges at row*64) vs compact (rp = row_ptr[]).

template <bool SRC_BF, bool DST_BF, bool X_BF, bool PAD>
__global__ __launch_bounds__(256) void row_spmm_t(const int* __restrict__ rp,
                                                  const int2* __restrict__ csr,
                                                  const void* __restrict__ xsrc,
                                                  const void* __restrict__ src,
                                                  void* __restrict__ dst) {
    int row = (blockIdx.x * 256 + threadIdx.x) >> 6;
    int lane = threadIdx.x & 63;
    if (row >= N_NODES) return;
    int beg, end;
    if (PAD) {
        int cn = rp[row];
        cn = (cn < MAXDEG) ? cn : MAXDEG;
        beg = row << 6;
        end = beg + cn;
    } else {
        beg = rp[row];
        end = rp[row + 1];
    }

    // x-term: issued early, overlaps the gather chain.
    float xtx, xty;
    if (X_BF) {
        unsigned u = ((const unsigned*)xsrc)[(size_t)row * 64 + lane];
        xtx = ALPHA * bf2f(u & 0xffffu);
        xty = ALPHA * bf2f(u >> 16);
    } else {
        float2 xv = ((const float2*)xsrc)[(size_t)row * 64 + lane];
        xtx = ALPHA * xv.x;
        xty = ALPHA * xv.y;
    }

    const float2*   sf = (const float2*)src;
    const unsigned* sb = (const unsigned*)src;

    float ax[4] = {0.f, 0.f, 0.f, 0.f};
    float ay[4] = {0.f, 0.f, 0.f, 0.f};

    auto gather = [&](int col) -> float2 {
        if (SRC_BF) {
            unsigned u = sb[(size_t)col * 64 + lane];
            float2 v;
            v.x = bf2f(u & 0xffffu);
            v.y = bf2f(u >> 16);
            return v;
        } else {
            return sf[(size_t)col * 64 + lane];
        }
    };

    int j = beg;
    // unroll x16: 16 outstanding 256B gathers per wave.
    while (j + 16 <= end) {
        int2 cw[16];
        #pragma unroll
        for (int u = 0; u < 16; ++u) cw[u] = csr[j + u];
        float2 v[16];
        #pragma unroll
        for (int u = 0; u < 16; ++u) v[u] = gather(cw[u].x);
        #pragma unroll
        for (int u = 0; u < 16; ++u) {
            float wv = __int_as_float(cw[u].y);
            ax[u & 3] += wv * v[u].x;
            ay[u & 3] += wv * v[u].y;
        }
        j += 16;
    }
    while (j + 8 <= end) {
        int2 cw[8];
        #pragma unroll
        for (int u = 0; u < 8; ++u) cw[u] = csr[j + u];
        float2 v[8];
        #pragma unroll
        for (int u = 0; u < 8; ++u) v[u] = gather(cw[u].x);
        #pragma unroll
        for (int u = 0; u < 8; ++u) {
            float wv = __int_as_float(cw[u].y);
            ax[u & 3] += wv * v[u].x;
            ay[u & 3] += wv * v[u].y;
        }
        j += 8;
    }
    while (j + 4 <= end) {
        int2 cw[4];
        #pragma unroll
        for (int u = 0; u < 4; ++u) cw[u] = csr[j + u];
        float2 v[4];
        #pragma unroll
        for (int u = 0; u < 4; ++u) v[u] = gather(cw[u].x);
        #pragma unroll
        for (int u = 0; u < 4; ++u) {
            float wv = __int_as_float(cw[u].y);
            ax[u] += wv * v[u].x;
            ay[u] += wv * v[u].y;
        }
        j += 4;
    }
    for (; j < end; ++j) {
        int2 cw = csr[j];
        float2 v = gather(cw.x);
        float wv = __int_as_float(cw.y);
        ax[0] += wv * v.x;
        ay[0] += wv * v.y;
    }

    float ox = xtx + (ax[0] + ax[1]) + (ax[2] + ax[3]);
    float oy = xty + (ay[0] + ay[1]) + (ay[2] + ay[3]);

    if (DST_BF) {
        ((unsigned*)dst)[(size_t)row * 64 + lane] = f2bf(ox) | (f2bf(oy) << 16);
    } else {
        float2 o; o.x = ox; o.y = oy;
        ((float2*)dst)[(size_t)row * 64 + lane] = o;
    }
}

// ---------- fallback (R0 atomic path) if ws too small ----------

__global__ __launch_bounds__(256) void init_step(const float4* __restrict__ x,
                                                 float4* __restrict__ dst, int n4) {
    int i = blockIdx.x * 256 + threadIdx.x;
    if (i < n4) {
        float4 v = x[i];
        dst[i] = make_float4(ALPHA * v.x, ALPHA * v.y, ALPHA * v.z, ALPHA * v.w);
    }
}

__global__ __launch_bounds__(256) void edge_scatter(const int* __restrict__ rows,
                                                    const int* __restrict__ cols,
                                                    const float* __restrict__ w,
                                                    const float* __restrict__ h,
                                                    float* __restrict__ dst) {
    unsigned t = blockIdx.x * 256u + threadIdx.x;
    unsigned e = t >> 5;
    unsigned l = t & 31u;
    if (e >= N_EDGES) return;
    int r = rows[e];
    int c = cols[e];
    float we = (1.0f - ALPHA) * w[e];
    const float4* hc = (const float4*)(h + (size_t)c * D_FEAT);
    float4 v = hc[l];
    float* dr = dst + (size_t)r * D_FEAT + (size_t)l * 4;
    unsafeAtomicAdd(dr + 0, we * v.x);
    unsafeAtomicAdd(dr + 1, we * v.y);
    unsafeAtomicAdd(dr + 2, we * v.z);
    unsafeAtomicAdd(dr + 3, we * v.w);
}

extern "C" void kernel_launch(void* const* d_in, const int* in_sizes, int n_in,
                              void* d_out, int out_size, void* d_ws, size_t ws_size,
                              hipStream_t stream) {
    const float* x  = (const float*)d_in[0];
    const int*   ei = (const int*)d_in[1];  // [2, E] flat: rows then cols
    const float* ev = (const float*)d_in[2];
    const int* rows = ei;
    const int* cols = ei + N_EDGES;
    float* out = (float*)d_out;

    auto align512 = [](size_t o) { return (o + 511) & ~(size_t)511; };

    // --- padded layout (tier 1), 512B-aligned: ha, hb, xb, cnt+gcount, csrp.
    // gbuf (pass-A bucket buffer, 50.2 MB) aliases contiguous [hb, xb) which
    // are dead during the build; x_to_bf16 runs after bucket_to_csr.
    size_t p_off = 0;
    size_t p_ha   = p_off; p_off = align512(p_off + (size_t)N_NODES * D_FEAT * 2);
    size_t p_hb   = p_off; p_off = align512(p_off + (size_t)N_NODES * D_FEAT * 2);
    size_t p_xb   = p_off; p_off = align512(p_off + (size_t)N_NODES * D_FEAT * 2);
    size_t p_cnt  = p_off; p_off = align512(p_off + (size_t)N_NODES * 4 + NBUCK * 4);
    size_t p_csr  = p_off; p_off = align512(p_off + (size_t)N_NODES * MAXDEG * 8);
    size_t need_pad = p_off;  // ~128.6 MB
    static_assert((size_t)NBUCK * BCAP * 16 <= 2 * (size_t)N_NODES * D_FEAT * 2,
                  "gbuf must fit in hb+xb");

    // --- compact layout (tiers 2/3): ha, hb, rowptr, cursor, partial, csr, [xb] ---
    size_t c_off = 0;
    size_t c_ha      = c_off; c_off = align512(c_off + (size_t)N_NODES * D_FEAT * 2);
    size_t c_hb      = c_off; c_off = align512(c_off + (size_t)N_NODES * D_FEAT * 2);
    size_t c_rowptr  = c_off; c_off = align512(c_off + (size_t)(N_NODES + 1) * 4);
    size_t c_cursor  = c_off; c_off = align512(c_off + (size_t)N_NODES * 4);
    size_t c_partial = c_off; c_off = align512(c_off + (size_t)SCAN_NBLK * 4);
    size_t c_csr     = c_off; c_off = align512(c_off + (size_t)N_EDGES * 8);
    size_t need_base = c_off;  // ~64.8 MB
    size_t c_xb      = c_off; c_off = align512(c_off + (size_t)N_NODES * D_FEAT * 2);
    size_t need_xb   = c_off;  // ~90.4 MB

    const int row_blocks = (N_NODES * 64 + 255) / 256;  // 25000 (1 wave/row)
    const float2* x2 = (const float2*)x;

    if (ws_size >= need_pad) {
        // ---- tier 1: bucketed padded CSR build + R8 spmm ----
        char* ws = (char*)d_ws;
        void*     h_a    = (void*)(ws + p_ha);
        void*     h_b    = (void*)(ws + p_hb);
        unsigned* xb     = (unsigned*)(ws + p_xb);
        int*      cnt    = (int*)(ws + p_cnt);
        int*      gcount = cnt + N_NODES;
        int2*     csrp   = (int2*)(ws + p_csr);
        int4*     gbuf   = (int4*)(ws + p_hb);  // aliases hb+xb during build

        hipMemsetAsync(cnt, 0, (size_t)N_NODES * 4 + NBUCK * 4, stream);
        const int blocks_a = (N_EDGES + EPB_A - 1) / EPB_A;  // 782
        bucket_scatter<<<blocks_a, 256, 0, stream>>>(rows, cols, ev, gcount, gbuf);
        bucket_to_csr<<<NBUCK, 256, 0, stream>>>(gcount, gbuf, cnt, csrp);

        const int nxb = N_NODES * D_FEAT / 2;
        x_to_bf16<<<(nxb + 255) / 256, 256, 0, stream>>>(x2, xb, nxb);

        row_spmm_t<true, true, true, true><<<row_blocks, 256, 0, stream>>>(
            cnt, csrp, (const void*)xb, (const void*)xb, h_a);
        for (int k = 1; k <= 8; ++k) {
            const void* src = (k & 1) ? h_a : h_b;
            void* dst = (k & 1) ? h_b : h_a;
            row_spmm_t<true, true, true, true><<<row_blocks, 256, 0, stream>>>(
                cnt, csrp, (const void*)xb, src, dst);
        }
        row_spmm_t<true, false, false, true><<<row_blocks, 256, 0, stream>>>(
            cnt, csrp, (const void*)x2, (const void*)h_a, (void*)out);
    } else if (ws_size >= need_base) {
        // ---- tiers 2/3: compact CSR (R5 path) ----
        char* ws = (char*)d_ws;
        void*  h_a     = (void*)(ws + c_ha);
        void*  h_b     = (void*)(ws + c_hb);
        int*   row_ptr = (int*)(ws + c_rowptr);
        int*   cursor  = (int*)(ws + c_cursor);
        int*   partial = (int*)(ws + c_partial);
        int2*  csr     = (int2*)(ws + c_csr);
        unsigned* xb   = (unsigned*)(ws + c_xb);
        const bool has_xb = (ws_size >= need_xb);
        const int edge_blocks_1t = (N_EDGES + 255) / 256;  // 6250

        hipMemsetAsync(cursor, 0, (size_t)N_NODES * 4, stream);
        hist_kernel<<<edge_blocks_1t, 256, 0, stream>>>(rows, cursor);
        scan_partial<<<SCAN_NBLK, 256, 0, stream>>>(cursor, partial);
        scan_top<<<1, 256, 0, stream>>>(partial);
        scan_final<<<SCAN_NBLK, 256, 0, stream>>>(cursor, partial, row_ptr);
        scatter_kernel<<<edge_blocks_1t, 256, 0, stream>>>(rows, cols, ev, cursor, csr);

        if (has_xb) {
            const int nxb = N_NODES * D_FEAT / 2;
            x_to_bf16<<<(nxb + 255) / 256, 256, 0, stream>>>(x2, xb, nxb);
            row_spmm_t<true, true, true, false><<<row_blocks, 256, 0, stream>>>(
                row_ptr, csr, (const void*)xb, (const void*)xb, h_a);
            for (int k = 1; k <= 8; ++k) {
                const void* src = (k & 1) ? h_a : h_b;
                void* dst = (k & 1) ? h_b : h_a;
                row_spmm_t<true, true, true, false><<<row_blocks, 256, 0, stream>>>(
                    row_ptr, csr, (const void*)xb, src, dst);
            }
            row_spmm_t<true, false, false, false><<<row_blocks, 256, 0, stream>>>(
                row_ptr, csr, (const void*)x2, (const void*)h_a, (void*)out);
        } else {
            row_spmm_t<false, true, false, false><<<row_blocks, 256, 0, stream>>>(
                row_ptr, csr, (const void*)x2, (const void*)x, h_a);
            for (int k = 1; k <= 8; ++k) {
                const void* src = (k & 1) ? h_a : h_b;
                void* dst = (k & 1) ? h_b : h_a;
                row_spmm_t<true, true, false, false><<<row_blocks, 256, 0, stream>>>(
                    row_ptr, csr, (const void*)x2, src, dst);
            }
            row_spmm_t<true, false, false, false><<<row_blocks, 256, 0, stream>>>(
                row_ptr, csr, (const void*)x2, (const void*)h_a, (void*)out);
        }
    } else {
        // Fallback: R0 atomic path (needs only the 51.2 MB ping buffer)
        float* wsf = (float*)d_ws;
        const int n4 = N_NODES * D_FEAT / 4;
        const int init_blocks = (n4 + 255) / 256;
        const int edge_blocks = (N_EDGES * 32 + 255) / 256;
        for (int k = 0; k < K_STEPS; ++k) {
            const float* src = (k == 0) ? x : ((k & 1) ? wsf : out);
            float* dst = (k & 1) ? out : wsf;
            init_step<<<init_blocks, 256, 0, stream>>>((const float4*)x, (float4*)dst, n4);
            edge_scatter<<<edge_blocks, 256, 0, stream>>>(rows, cols, ev, src, dst);
        }
    }
}

// Round 11
// 777.689 us; speedup vs baseline: 1.2150x; 1.0343x over previous
//
#include <hip/hip_runtime.h>

// APPNP propagation: h <- (1-alpha) * A @ h + alpha * x, K=10 steps.
// R8: padded CSR + x16 unroll -> 864.6. R11: sw-pipeline REGRESSED (944.9).
// R13: bucketed build v2 (grid=NBUCK, 512B-aligned) -> 804.3. spmm counters:
//     73.3us/step, FETCH 212 MB (was 280 in R10), VALUBusy 45%. FETCH dropped
//     68MB with NO time change vs R8 -> spmm NOT fabric-byte-bound; joint
//     VALU/issue + memory. Per-wave cost: ~1 VMEM + ~9-10 VALU per edge.
// R14: tier-1 spmm re-mapped to 4-edges-per-instruction (row_spmm_q):
//     lane l = (sub=l>>4, fl=l&15); lane loads its OWN csr[j+sub] (col+w,
//     no cross-lane select) and dwordx4 16B = 8 bf16 feats of its sub-edge.
//     1 gather instr = 4 edges (1KB), 1 csr instr = 4 edges. Per-edge VALU
//     ~halved, VMEM instrs ~halved; bytes + line requests + edges-in-flight
//     (8/wave) identical -> pure instruction-stream cut. Epilogue: shfl_xor
//     16/32 reduce, sub==0 lanes store 16B. Masked tails; csrp +512B slack.
//     Build (bucketed v2) and fallback tiers unchanged.

#define N_NODES 100000
#define N_EDGES 1600000
#define D_FEAT  128
#define ALPHA   0.1f
#define K_STEPS 10
#define MAXDEG  64   // P(Poisson(16) >= 64) ~ 1e-19; guarded anyway

#define NBUCK 196    // buckets of 512 rows: (N_NODES + 511) >> 9
#define BCAP  16000  // entries/bucket; mean 8192, cap ~ +86 sigma
#define EPB_A 2048   // edges per block in pass A

#define SCAN_ELEMS 512
#define SCAN_NBLK  ((N_NODES + SCAN_ELEMS - 1) / SCAN_ELEMS)  // 196

static __device__ __forceinline__ float bf2f(unsigned u16) {
    return __uint_as_float(u16 << 16);
}
static __device__ __forceinline__ unsigned f2bf(float f) {
    unsigned u = __float_as_uint(f);
    return (u + 0x7fffu + ((u >> 16) & 1u)) >> 16;  // round-to-nearest-even
}

// ---------- bucketed CSR build (tier 1, R13-exact) ----------

__global__ __launch_bounds__(256) void bucket_scatter(const int* __restrict__ rows,
                                                      const int* __restrict__ cols,
                                                      const float* __restrict__ w,
                                                      int* __restrict__ gcount,
                                                      int4* __restrict__ gbuf) {
    __shared__ int h_cnt[NBUCK];
    __shared__ int h_base[NBUCK];
    __shared__ int h_cur[NBUCK];
    const int tid = threadIdx.x;
    for (int i = tid; i < NBUCK; i += 256) { h_cnt[i] = 0; h_cur[i] = 0; }
    __syncthreads();

    const int base_e = blockIdx.x * EPB_A + tid;
    int er[8]; int ec[8]; float ew[8];
    #pragma unroll
    for (int k = 0; k < 8; ++k) {
        int e = base_e + k * 256;
        bool v = (e < N_EDGES);
        er[k] = v ? rows[e] : -1;
        ec[k] = v ? cols[e] : 0;
        ew[k] = v ? w[e] : 0.f;
        if (v) atomicAdd(&h_cnt[er[k] >> 9], 1);
    }
    __syncthreads();
    for (int i = tid; i < NBUCK; i += 256) {
        h_base[i] = (h_cnt[i] > 0) ? atomicAdd(&gcount[i], h_cnt[i]) : 0;
    }
    __syncthreads();
    #pragma unroll
    for (int k = 0; k < 8; ++k) {
        if (er[k] >= 0) {
            int b = er[k] >> 9;
            int p = h_base[b] + atomicAdd(&h_cur[b], 1);
            if (p < BCAP) {
                int4 ent;
                ent.x = er[k];
                ent.y = ec[k];
                ent.z = __float_as_int((1.0f - ALPHA) * ew[k]);  // fold 0.9
                ent.w = 0;
                gbuf[(size_t)b * BCAP + p] = ent;
            }
        }
    }
}

__global__ __launch_bounds__(256) void bucket_to_csr(const int* __restrict__ gcount,
                                                     const int4* __restrict__ gbuf,
                                                     int* __restrict__ cnt,
                                                     int2* __restrict__ csrp) {
    __shared__ int rcur[512];
    const int tid = threadIdx.x;
    const int b = blockIdx.x;  // grid == NBUCK: one bucket per block
    for (int i = tid; i < 512; i += 256) rcur[i] = 0;
    __syncthreads();
    int n = gcount[b];
    if (n > BCAP) n = BCAP;
    for (int i = tid; i < n; i += 256) {
        int4 e = gbuf[(size_t)b * BCAP + i];
        int p = atomicAdd(&rcur[e.x & 511], 1);  // LDS atomic: position
        if (p < MAXDEG) {
            int2 cw;
            cw.x = e.y;
            cw.y = e.z;
            csrp[((size_t)e.x << 6) + p] = cw;
        }
    }
    __syncthreads();
    const int rowbase = b << 9;
    for (int i = tid; i < 512; i += 256) {
        int row = rowbase + i;
        if (row < N_NODES) cnt[row] = rcur[i];  // spmm clamps to MAXDEG
    }
}

// ---------- compact CSR build (fallback tier, R5 path) ----------

__global__ __launch_bounds__(256) void hist_kernel(const int* __restrict__ rows,
                                                   int* __restrict__ deg) {
    int e = blockIdx.x * 256 + threadIdx.x;
    if (e < N_EDGES) atomicAdd(&deg[rows[e]], 1);
}

__global__ __launch_bounds__(256) void scan_partial(const int* __restrict__ deg,
                                                    int* __restrict__ partial) {
    __shared__ int s[256];
    int b = blockIdx.x, t = threadIdx.x;
    int i0 = b * SCAN_ELEMS + t * 2;
    int v0 = (i0 < N_NODES) ? deg[i0] : 0;
    int v1 = (i0 + 1 < N_NODES) ? deg[i0 + 1] : 0;
    s[t] = v0 + v1;
    __syncthreads();
    for (int off = 128; off > 0; off >>= 1) {
        if (t < off) s[t] += s[t + off];
        __syncthreads();
    }
    if (t == 0) partial[b] = s[0];
}

__global__ __launch_bounds__(256) void scan_top(int* __restrict__ partial) {
    __shared__ int s[256];
    int t = threadIdx.x;
    s[t] = (t < SCAN_NBLK) ? partial[t] : 0;
    __syncthreads();
    for (int off = 1; off < 256; off <<= 1) {
        int v = (t >= off) ? s[t - off] : 0;
        __syncthreads();
        s[t] += v;
        __syncthreads();
    }
    if (t < SCAN_NBLK) partial[t] = (t == 0) ? 0 : s[t - 1];
}

__global__ __launch_bounds__(256) void scan_final(int* __restrict__ deg_cursor,
                                                  const int* __restrict__ partial,
                                                  int* __restrict__ row_ptr) {
    __shared__ int s[256];
    int b = blockIdx.x, t = threadIdx.x;
    int i0 = b * SCAN_ELEMS + t * 2;
    int v0 = (i0 < N_NODES) ? deg_cursor[i0] : 0;
    int v1 = (i0 + 1 < N_NODES) ? deg_cursor[i0 + 1] : 0;
    int pair = v0 + v1;
    s[t] = pair;
    __syncthreads();
    for (int off = 1; off < 256; off <<= 1) {
        int v = (t >= off) ? s[t - off] : 0;
        __syncthreads();
        s[t] += v;
        __syncthreads();
    }
    int ex = partial[b] + s[t] - pair;  // exclusive prefix of element 2t
    if (i0 < N_NODES)     { row_ptr[i0] = ex;          deg_cursor[i0] = ex; }
    if (i0 + 1 < N_NODES) { row_ptr[i0 + 1] = ex + v0; deg_cursor[i0 + 1] = ex + v0; }
    if (b == 0 && t == 0) row_ptr[N_NODES] = N_EDGES;
}

__global__ __launch_bounds__(256) void scatter_kernel(const int* __restrict__ rows,
                                                      const int* __restrict__ cols,
                                                      const float* __restrict__ w,
                                                      int* __restrict__ cursor,
                                                      int2* __restrict__ csr) {
    int e = blockIdx.x * 256 + threadIdx.x;
    if (e < N_EDGES) {
        int pos = atomicAdd(&cursor[rows[e]], 1);
        int2 cw;
        cw.x = cols[e];
        cw.y = __float_as_int((1.0f - ALPHA) * w[e]);  // fold 0.9 into the weight
        csr[pos] = cw;
    }
}

// x fp32 -> packed 2xbf16 per u32 (row-major, 64 u32 per row)
__global__ __launch_bounds__(256) void x_to_bf16(const float2* __restrict__ x2,
                                                 unsigned* __restrict__ xb, int n) {
    int i = blockIdx.x * 256 + threadIdx.x;
    if (i < n) {
        float2 v = x2[i];
        xb[i] = f2bf(v.x) | (f2bf(v.y) << 16);
    }
}

// ---------- tier-1 propagation: 4 edges per instruction ----------
// Lane l = (sub = l>>4, fl = l&15). Lane's csr entry: csr[j+sub] (own col+w).
// Lane's gather: 16B (8 bf16 feats 8*fl..8*fl+7) of its sub-edge's source row.
// After the loop: shfl_xor(16,32) sums the 4 sub-groups; sub==0 lanes store.
// DST_BF: bf16 dst (uint4/row-slice) vs fp32. X_BF: bf16 xb vs fp32 x.

template <bool DST_BF, bool X_BF>
__global__ __launch_bounds__(256) void row_spmm_q(const int* __restrict__ rp,
                                                  const int2* __restrict__ csr,
                                                  const void* __restrict__ xsrc,
                                                  const unsigned* __restrict__ src,
                                                  void* __restrict__ dst) {
    int row = (blockIdx.x * 256 + threadIdx.x) >> 6;
    int lane = threadIdx.x & 63;
    if (row >= N_NODES) return;
    int cn = rp[row];
    cn = (cn < MAXDEG) ? cn : MAXDEG;
    const int beg = row << 6;
    const int end = beg + cn;
    const int sub = lane >> 4;
    const int fl  = lane & 15;

    // x-term slice for this lane's 8 features: issued early, used at epilogue.
    uint4 xu; float4 xa, xc;
    if (X_BF) {
        xu = ((const uint4*)xsrc)[(size_t)row * 16 + fl];
    } else {
        xa = ((const float4*)xsrc)[(size_t)row * 32 + 2 * fl];
        xc = ((const float4*)xsrc)[(size_t)row * 32 + 2 * fl + 1];
    }

    const uint4* s4 = (const uint4*)src;  // row = 16 uint4; slice fl

    float acc[8];
    #pragma unroll
    for (int k = 0; k < 8; ++k) acc[k] = 0.f;

    for (int j = beg; j < end; j += 8) {
        int i0 = j + sub;
        int i1 = j + 4 + sub;
        bool v0 = i0 < end;
        bool v1 = i1 < end;
        int2 c0 = csr[i0];  // <= 48B past last row's window; csrp has slack
        int2 c1 = csr[i1];
        int col0 = v0 ? c0.x : 0;
        int col1 = v1 ? c1.x : 0;
        float w0 = v0 ? __int_as_float(c0.y) : 0.f;
        float w1 = v1 ? __int_as_float(c1.y) : 0.f;
        uint4 g0 = s4[(size_t)col0 * 16 + fl];
        uint4 g1 = s4[(size_t)col1 * 16 + fl];
        acc[0] += w0 * bf2f(g0.x & 0xffffu);
        acc[1] += w0 * bf2f(g0.x >> 16);
        acc[2] += w0 * bf2f(g0.y & 0xffffu);
        acc[3] += w0 * bf2f(g0.y >> 16);
        acc[4] += w0 * bf2f(g0.z & 0xffffu);
        acc[5] += w0 * bf2f(g0.z >> 16);
        acc[6] += w0 * bf2f(g0.w & 0xffffu);
        acc[7] += w0 * bf2f(g0.w >> 16);
        acc[0] += w1 * bf2f(g1.x & 0xffffu);
        acc[1] += w1 * bf2f(g1.x >> 16);
        acc[2] += w1 * bf2f(g1.y & 0xffffu);
        acc[3] += w1 * bf2f(g1.y >> 16);
        acc[4] += w1 * bf2f(g1.z & 0xffffu);
        acc[5] += w1 * bf2f(g1.z >> 16);
        acc[6] += w1 * bf2f(g1.w & 0xffffu);
        acc[7] += w1 * bf2f(g1.w >> 16);
    }

    // Sum the 4 sub-groups (lanes fl, fl+16, fl+32, fl+48 share features).
    #pragma unroll
    for (int k = 0; k < 8; ++k) {
        acc[k] += __shfl_xor(acc[k], 16);
        acc[k] += __shfl_xor(acc[k], 32);
    }

    // alpha * x
    if (X_BF) {
        acc[0] += ALPHA * bf2f(xu.x & 0xffffu);
        acc[1] += ALPHA * bf2f(xu.x >> 16);
        acc[2] += ALPHA * bf2f(xu.y & 0xffffu);
        acc[3] += ALPHA * bf2f(xu.y >> 16);
        acc[4] += ALPHA * bf2f(xu.z & 0xffffu);
        acc[5] += ALPHA * bf2f(xu.z >> 16);
        acc[6] += ALPHA * bf2f(xu.w & 0xffffu);
        acc[7] += ALPHA * bf2f(xu.w >> 16);
    } else {
        acc[0] += ALPHA * xa.x; acc[1] += ALPHA * xa.y;
        acc[2] += ALPHA * xa.z; acc[3] += ALPHA * xa.w;
        acc[4] += ALPHA * xc.x; acc[5] += ALPHA * xc.y;
        acc[6] += ALPHA * xc.z; acc[7] += ALPHA * xc.w;
    }

    if (DST_BF) {
        if (sub == 0) {
            uint4 o;
            o.x = f2bf(acc[0]) | (f2bf(acc[1]) << 16);
            o.y = f2bf(acc[2]) | (f2bf(acc[3]) << 16);
            o.z = f2bf(acc[4]) | (f2bf(acc[5]) << 16);
            o.w = f2bf(acc[6]) | (f2bf(acc[7]) << 16);
            ((uint4*)dst)[(size_t)row * 16 + fl] = o;
        }
    } else {
        if (sub == 0) {
            float4 o; o.x = acc[0]; o.y = acc[1]; o.z = acc[2]; o.w = acc[3];
            ((float4*)dst)[(size_t)row * 32 + 2 * fl] = o;
        } else if (sub == 1) {
            float4 o; o.x = acc[4]; o.y = acc[5]; o.z = acc[6]; o.w = acc[7];
            ((float4*)dst)[(size_t)row * 32 + 2 * fl + 1] = o;
        }
    }
}

// ---------- propagation (fallback tiers, R8-exact) ----------

template <bool SRC_BF, bool DST_BF, bool X_BF, bool PAD>
__global__ __launch_bounds__(256) void row_spmm_t(const int* __restrict__ rp,
                                                  const int2* __restrict__ csr,
                                                  const void* __restrict__ xsrc,
                                                  const void* __restrict__ src,
                                                  void* __restrict__ dst) {
    int row = (blockIdx.x * 256 + threadIdx.x) >> 6;
    int lane = threadIdx.x & 63;
    if (row >= N_NODES) return;
    int beg, end;
    if (PAD) {
        int cn = rp[row];
        cn = (cn < MAXDEG) ? cn : MAXDEG;
        beg = row << 6;
        end = beg + cn;
    } else {
        beg = rp[row];
        end = rp[row + 1];
    }

    float xtx, xty;
    if (X_BF) {
        unsigned u = ((const unsigned*)xsrc)[(size_t)row * 64 + lane];
        xtx = ALPHA * bf2f(u & 0xffffu);
        xty = ALPHA * bf2f(u >> 16);
    } else {
        float2 xv = ((const float2*)xsrc)[(size_t)row * 64 + lane];
        xtx = ALPHA * xv.x;
        xty = ALPHA * xv.y;
    }

    const float2*   sf = (const float2*)src;
    const unsigned* sb = (const unsigned*)src;

    float ax[4] = {0.f, 0.f, 0.f, 0.f};
    float ay[4] = {0.f, 0.f, 0.f, 0.f};

    auto gather = [&](int col) -> float2 {
        if (SRC_BF) {
            unsigned u = sb[(size_t)col * 64 + lane];
            float2 v;
            v.x = bf2f(u & 0xffffu);
            v.y = bf2f(u >> 16);
            return v;
        } else {
            return sf[(size_t)col * 64 + lane];
        }
    };

    int j = beg;
    while (j + 8 <= end) {
        int2 cw[8];
        #pragma unroll
        for (int u = 0; u < 8; ++u) cw[u] = csr[j + u];
        float2 v[8];
        #pragma unroll
        for (int u = 0; u < 8; ++u) v[u] = gather(cw[u].x);
        #pragma unroll
        for (int u = 0; u < 8; ++u) {
            float wv = __int_as_float(cw[u].y);
            ax[u & 3] += wv * v[u].x;
            ay[u & 3] += wv * v[u].y;
        }
        j += 8;
    }
    while (j + 4 <= end) {
        int2 cw[4];
        #pragma unroll
        for (int u = 0; u < 4; ++u) cw[u] = csr[j + u];
        float2 v[4];
        #pragma unroll
        for (int u = 0; u < 4; ++u) v[u] = gather(cw[u].x);
        #pragma unroll
        for (int u = 0; u < 4; ++u) {
            float wv = __int_as_float(cw[u].y);
            ax[u] += wv * v[u].x;
            ay[u] += wv * v[u].y;
        }
        j += 4;
    }
    for (; j < end; ++j) {
        int2 cw = csr[j];
        float2 v = gather(cw.x);
        float wv = __int_as_float(cw.y);
        ax[0] += wv * v.x;
        ay[0] += wv * v.y;
    }

    float ox = xtx + (ax[0] + ax[1]) + (ax[2] + ax[3]);
    float oy = xty + (ay[0] + ay[1]) + (ay[2] + ay[3]);

    if (DST_BF) {
        ((unsigned*)dst)[(size_t)row * 64 + lane] = f2bf(ox) | (f2bf(oy) << 16);
    } else {
        float2 o; o.x = ox; o.y = oy;
        ((float2*)dst)[(size_t)row * 64 + lane] = o;
    }
}

// ---------- fallback (R0 atomic path) if ws too small ----------

__global__ __launch_bounds__(256) void init_step(const float4* __restrict__ x,
                                                 float4* __restrict__ dst, int n4) {
    int i = blockIdx.x * 256 + threadIdx.x;
    if (i < n4) {
        float4 v = x[i];
        dst[i] = make_float4(ALPHA * v.x, ALPHA * v.y, ALPHA * v.z, ALPHA * v.w);
    }
}

__global__ __launch_bounds__(256) void edge_scatter(const int* __restrict__ rows,
                                                    const int* __restrict__ cols,
                                                    const float* __restrict__ w,
                                                    const float* __restrict__ h,
                                                    float* __restrict__ dst) {
    unsigned t = blockIdx.x * 256u + threadIdx.x;
    unsigned e = t >> 5;
    unsigned l = t & 31u;
    if (e >= N_EDGES) return;
    int r = rows[e];
    int c = cols[e];
    float we = (1.0f - ALPHA) * w[e];
    const float4* hc = (const float4*)(h + (size_t)c * D_FEAT);
    float4 v = hc[l];
    float* dr = dst + (size_t)r * D_FEAT + (size_t)l * 4;
    unsafeAtomicAdd(dr + 0, we * v.x);
    unsafeAtomicAdd(dr + 1, we * v.y);
    unsafeAtomicAdd(dr + 2, we * v.z);
    unsafeAtomicAdd(dr + 3, we * v.w);
}

extern "C" void kernel_launch(void* const* d_in, const int* in_sizes, int n_in,
                              void* d_out, int out_size, void* d_ws, size_t ws_size,
                              hipStream_t stream) {
    const float* x  = (const float*)d_in[0];
    const int*   ei = (const int*)d_in[1];  // [2, E] flat: rows then cols
    const float* ev = (const float*)d_in[2];
    const int* rows = ei;
    const int* cols = ei + N_EDGES;
    float* out = (float*)d_out;

    auto align512 = [](size_t o) { return (o + 511) & ~(size_t)511; };

    // --- padded layout (tier 1), 512B-aligned: ha, hb, xb, cnt+gcount, csrp.
    // gbuf (pass-A bucket buffer, 50.2 MB) aliases contiguous [hb, xb).
    // csrp gets +512B slack for the masked tail over-read in row_spmm_q.
    size_t p_off = 0;
    size_t p_ha   = p_off; p_off = align512(p_off + (size_t)N_NODES * D_FEAT * 2);
    size_t p_hb   = p_off; p_off = align512(p_off + (size_t)N_NODES * D_FEAT * 2);
    size_t p_xb   = p_off; p_off = align512(p_off + (size_t)N_NODES * D_FEAT * 2);
    size_t p_cnt  = p_off; p_off = align512(p_off + (size_t)N_NODES * 4 + NBUCK * 4);
    size_t p_csr  = p_off; p_off = align512(p_off + (size_t)N_NODES * MAXDEG * 8 + 512);
    size_t need_pad = p_off;  // ~128.6 MB
    static_assert((size_t)NBUCK * BCAP * 16 <= 2 * (size_t)N_NODES * D_FEAT * 2,
                  "gbuf must fit in hb+xb");

    // --- compact layout (tiers 2/3): ha, hb, rowptr, cursor, partial, csr, [xb] ---
    size_t c_off = 0;
    size_t c_ha      = c_off; c_off = align512(c_off + (size_t)N_NODES * D_FEAT * 2);
    size_t c_hb      = c_off; c_off = align512(c_off + (size_t)N_NODES * D_FEAT * 2);
    size_t c_rowptr  = c_off; c_off = align512(c_off + (size_t)(N_NODES + 1) * 4);
    size_t c_cursor  = c_off; c_off = align512(c_off + (size_t)N_NODES * 4);
    size_t c_partial = c_off; c_off = align512(c_off + (size_t)SCAN_NBLK * 4);
    size_t c_csr     = c_off; c_off = align512(c_off + (size_t)N_EDGES * 8);
    size_t need_base = c_off;  // ~64.8 MB
    size_t c_xb      = c_off; c_off = align512(c_off + (size_t)N_NODES * D_FEAT * 2);
    size_t need_xb   = c_off;  // ~90.4 MB

    const int row_blocks = (N_NODES * 64 + 255) / 256;  // 25000 (1 wave/row)
    const float2* x2 = (const float2*)x;

    if (ws_size >= need_pad) {
        // ---- tier 1: bucketed padded CSR build + 4-edge spmm ----
        char* ws = (char*)d_ws;
        void*     h_a    = (void*)(ws + p_ha);
        void*     h_b    = (void*)(ws + p_hb);
        unsigned* xb     = (unsigned*)(ws + p_xb);
        int*      cnt    = (int*)(ws + p_cnt);
        int*      gcount = cnt + N_NODES;
        int2*     csrp   = (int2*)(ws + p_csr);
        int4*     gbuf   = (int4*)(ws + p_hb);  // aliases hb+xb during build

        hipMemsetAsync(cnt, 0, (size_t)N_NODES * 4 + NBUCK * 4, stream);
        const int blocks_a = (N_EDGES + EPB_A - 1) / EPB_A;  // 782
        bucket_scatter<<<blocks_a, 256, 0, stream>>>(rows, cols, ev, gcount, gbuf);
        bucket_to_csr<<<NBUCK, 256, 0, stream>>>(gcount, gbuf, cnt, csrp);

        const int nxb = N_NODES * D_FEAT / 2;
        x_to_bf16<<<(nxb + 255) / 256, 256, 0, stream>>>(x2, xb, nxb);

        row_spmm_q<true, true><<<row_blocks, 256, 0, stream>>>(
            cnt, csrp, (const void*)xb, xb, h_a);
        for (int k = 1; k <= 8; ++k) {
            const void* src = (k & 1) ? h_a : h_b;
            void* dst = (k & 1) ? h_b : h_a;
            row_spmm_q<true, true><<<row_blocks, 256, 0, stream>>>(
                cnt, csrp, (const void*)xb, (const unsigned*)src, dst);
        }
        row_spmm_q<false, false><<<row_blocks, 256, 0, stream>>>(
            cnt, csrp, (const void*)x2, (const unsigned*)h_a, (void*)out);
    } else if (ws_size >= need_base) {
        // ---- tiers 2/3: compact CSR (R5 path) ----
        char* ws = (char*)d_ws;
        void*  h_a     = (void*)(ws + c_ha);
        void*  h_b     = (void*)(ws + c_hb);
        int*   row_ptr = (int*)(ws + c_rowptr);
        int*   cursor  = (int*)(ws + c_cursor);
        int*   partial = (int*)(ws + c_partial);
        int2*  csr     = (int2*)(ws + c_csr);
        unsigned* xb   = (unsigned*)(ws + c_xb);
        const bool has_xb = (ws_size >= need_xb);
        const int edge_blocks_1t = (N_EDGES + 255) / 256;  // 6250

        hipMemsetAsync(cursor, 0, (size_t)N_NODES * 4, stream);
        hist_kernel<<<edge_blocks_1t, 256, 0, stream>>>(rows, cursor);
        scan_partial<<<SCAN_NBLK, 256, 0, stream>>>(cursor, partial);
        scan_top<<<1, 256, 0, stream>>>(partial);
        scan_final<<<SCAN_NBLK, 256, 0, stream>>>(cursor, partial, row_ptr);
        scatter_kernel<<<edge_blocks_1t, 256, 0, stream>>>(rows, cols, ev, cursor, csr);

        if (has_xb) {
            const int nxb = N_NODES * D_FEAT / 2;
            x_to_bf16<<<(nxb + 255) / 256, 256, 0, stream>>>(x2, xb, nxb);
            row_spmm_t<true, true, true, false><<<row_blocks, 256, 0, stream>>>(
                row_ptr, csr, (const void*)xb, (const void*)xb, h_a);
            for (int k = 1; k <= 8; ++k) {
                const void* src = (k & 1) ? h_a : h_b;
                void* dst = (k & 1) ? h_b : h_a;
                row_spmm_t<true, true, true, false><<<row_blocks, 256, 0, stream>>>(
                    row_ptr, csr, (const void*)xb, src, dst);
            }
            row_spmm_t<true, false, false, false><<<row_blocks, 256, 0, stream>>>(
                row_ptr, csr, (const void*)x2, (const void*)h_a, (void*)out);
        } else {
            row_spmm_t<false, true, false, false><<<row_blocks, 256, 0, stream>>>(
                row_ptr, csr, (const void*)x2, (const void*)x, h_a);
            for (int k = 1; k <= 8; ++k) {
                const void* src = (k & 1) ? h_a : h_b;
                void* dst = (k & 1) ? h_b : h_a;
                row_spmm_t<true, true, false, false><<<row_blocks, 256, 0, stream>>>(
                    row_ptr, csr, (const void*)x2, src, dst);
            }
            row_spmm_t<true, false, false, false><<<row_blocks, 256, 0, stream>>>(
                row_ptr, csr, (const void*)x2, (const void*)h_a, (void*)out);
        }
    } else {
        // Fallback: R0 atomic path (needs only the 51.2 MB ping buffer)
        float* wsf = (float*)d_ws;
        const int n4 = N_NODES * D_FEAT / 4;
        const int init_blocks = (n4 + 255) / 256;
        const int edge_blocks = (N_EDGES * 32 + 255) / 256;
        for (int k = 0; k < K_STEPS; ++k) {
            const float* src = (k == 0) ? x : ((k & 1) ? wsf : out);
            float* dst = (k & 1) ? out : wsf;
            init_step<<<init_blocks, 256, 0, stream>>>((const float4*)x, (float4*)dst, n4);
            edge_scatter<<<edge_blocks, 256, 0, stream>>>(rows, cols, ev, src, dst);
        }
    }
}

// Round 12
// 766.950 us; speedup vs baseline: 1.2320x; 1.0140x over previous
//
#include <hip/hip_runtime.h>

// APPNP propagation: h <- (1-alpha) * A @ h + alpha * x, K=10 steps.
// R13: bucketed build v2 -> 804.3 (spmm 73.3us/step, FETCH 212MB).
// R14: 4-edges-per-instruction spmm -> 777.7; spmm 68us/step, VGPR 24,
//     VALUBusy 41% (FMA+unpack work is mapping-invariant), FETCH 212MB,
//     fetch rate crept 3.65->3.9 TB/s -> near a memory plateau; the one
//     untested dimension is per-wave MLP (2 gathers in flight).
// R15: MLP probe -- widen to 16 edges/iter: 4 csr loads + 4 independent 1KB
//     gathers in flight before first consume. Tail masking wastes ~43% of
//     gather slots but masked lanes hit col 0 (L2-hot line): costs L2 BW +
//     issue, NOT fabric. Decisive: MLP-limited -> ~58us/step (~690 total);
//     fabric-saturated -> unchanged -> declare roofline next round.

#define N_NODES 100000
#define N_EDGES 1600000
#define D_FEAT  128
#define ALPHA   0.1f
#define K_STEPS 10
#define MAXDEG  64   // P(Poisson(16) >= 64) ~ 1e-19; guarded anyway

#define NBUCK 196    // buckets of 512 rows: (N_NODES + 511) >> 9
#define BCAP  16000  // entries/bucket; mean 8192, cap ~ +86 sigma
#define EPB_A 2048   // edges per block in pass A

#define SCAN_ELEMS 512
#define SCAN_NBLK  ((N_NODES + SCAN_ELEMS - 1) / SCAN_ELEMS)  // 196

static __device__ __forceinline__ float bf2f(unsigned u16) {
    return __uint_as_float(u16 << 16);
}
static __device__ __forceinline__ unsigned f2bf(float f) {
    unsigned u = __float_as_uint(f);
    return (u + 0x7fffu + ((u >> 16) & 1u)) >> 16;  // round-to-nearest-even
}
// low feature of packed pair: bits<<16; high feature: mask (no shift needed)
static __device__ __forceinline__ float bflo(unsigned u) {
    return __uint_as_float(u << 16);
}
static __device__ __forceinline__ float bfhi(unsigned u) {
    return __uint_as_float(u & 0xffff0000u);
}

// ---------- bucketed CSR build (tier 1, R13-exact) ----------

__global__ __launch_bounds__(256) void bucket_scatter(const int* __restrict__ rows,
                                                      const int* __restrict__ cols,
                                                      const float* __restrict__ w,
                                                      int* __restrict__ gcount,
                                                      int4* __restrict__ gbuf) {
    __shared__ int h_cnt[NBUCK];
    __shared__ int h_base[NBUCK];
    __shared__ int h_cur[NBUCK];
    const int tid = threadIdx.x;
    for (int i = tid; i < NBUCK; i += 256) { h_cnt[i] = 0; h_cur[i] = 0; }
    __syncthreads();

    const int base_e = blockIdx.x * EPB_A + tid;
    int er[8]; int ec[8]; float ew[8];
    #pragma unroll
    for (int k = 0; k < 8; ++k) {
        int e = base_e + k * 256;
        bool v = (e < N_EDGES);
        er[k] = v ? rows[e] : -1;
        ec[k] = v ? cols[e] : 0;
        ew[k] = v ? w[e] : 0.f;
        if (v) atomicAdd(&h_cnt[er[k] >> 9], 1);
    }
    __syncthreads();
    for (int i = tid; i < NBUCK; i += 256) {
        h_base[i] = (h_cnt[i] > 0) ? atomicAdd(&gcount[i], h_cnt[i]) : 0;
    }
    __syncthreads();
    #pragma unroll
    for (int k = 0; k < 8; ++k) {
        if (er[k] >= 0) {
            int b = er[k] >> 9;
            int p = h_base[b] + atomicAdd(&h_cur[b], 1);
            if (p < BCAP) {
                int4 ent;
                ent.x = er[k];
                ent.y = ec[k];
                ent.z = __float_as_int((1.0f - ALPHA) * ew[k]);  // fold 0.9
                ent.w = 0;
                gbuf[(size_t)b * BCAP + p] = ent;
            }
        }
    }
}

__global__ __launch_bounds__(256) void bucket_to_csr(const int* __restrict__ gcount,
                                                     const int4* __restrict__ gbuf,
                                                     int* __restrict__ cnt,
                                                     int2* __restrict__ csrp) {
    __shared__ int rcur[512];
    const int tid = threadIdx.x;
    const int b = blockIdx.x;  // grid == NBUCK: one bucket per block
    for (int i = tid; i < 512; i += 256) rcur[i] = 0;
    __syncthreads();
    int n = gcount[b];
    if (n > BCAP) n = BCAP;
    for (int i = tid; i < n; i += 256) {
        int4 e = gbuf[(size_t)b * BCAP + i];
        int p = atomicAdd(&rcur[e.x & 511], 1);  // LDS atomic: position
        if (p < MAXDEG) {
            int2 cw;
            cw.x = e.y;
            cw.y = e.z;
            csrp[((size_t)e.x << 6) + p] = cw;
        }
    }
    __syncthreads();
    const int rowbase = b << 9;
    for (int i = tid; i < 512; i += 256) {
        int row = rowbase + i;
        if (row < N_NODES) cnt[row] = rcur[i];  // spmm clamps to MAXDEG
    }
}

// ---------- compact CSR build (fallback tier, R5 path) ----------

__global__ __launch_bounds__(256) void hist_kernel(const int* __restrict__ rows,
                                                   int* __restrict__ deg) {
    int e = blockIdx.x * 256 + threadIdx.x;
    if (e < N_EDGES) atomicAdd(&deg[rows[e]], 1);
}

__global__ __launch_bounds__(256) void scan_partial(const int* __restrict__ deg,
                                                    int* __restrict__ partial) {
    __shared__ int s[256];
    int b = blockIdx.x, t = threadIdx.x;
    int i0 = b * SCAN_ELEMS + t * 2;
    int v0 = (i0 < N_NODES) ? deg[i0] : 0;
    int v1 = (i0 + 1 < N_NODES) ? deg[i0 + 1] : 0;
    s[t] = v0 + v1;
    __syncthreads();
    for (int off = 128; off > 0; off >>= 1) {
        if (t < off) s[t] += s[t + off];
        __syncthreads();
    }
    if (t == 0) partial[b] = s[0];
}

__global__ __launch_bounds__(256) void scan_top(int* __restrict__ partial) {
    __shared__ int s[256];
    int t = threadIdx.x;
    s[t] = (t < SCAN_NBLK) ? partial[t] : 0;
    __syncthreads();
    for (int off = 1; off < 256; off <<= 1) {
        int v = (t >= off) ? s[t - off] : 0;
        __syncthreads();
        s[t] += v;
        __syncthreads();
    }
    if (t < SCAN_NBLK) partial[t] = (t == 0) ? 0 : s[t - 1];
}

__global__ __launch_bounds__(256) void scan_final(int* __restrict__ deg_cursor,
                                                  const int* __restrict__ partial,
                                                  int* __restrict__ row_ptr) {
    __shared__ int s[256];
    int b = blockIdx.x, t = threadIdx.x;
    int i0 = b * SCAN_ELEMS + t * 2;
    int v0 = (i0 < N_NODES) ? deg_cursor[i0] : 0;
    int v1 = (i0 + 1 < N_NODES) ? deg_cursor[i0 + 1] : 0;
    int pair = v0 + v1;
    s[t] = pair;
    __syncthreads();
    for (int off = 1; off < 256; off <<= 1) {
        int v = (t >= off) ? s[t - off] : 0;
        __syncthreads();
        s[t] += v;
        __syncthreads();
    }
    int ex = partial[b] + s[t] - pair;  // exclusive prefix of element 2t
    if (i0 < N_NODES)     { row_ptr[i0] = ex;          deg_cursor[i0] = ex; }
    if (i0 + 1 < N_NODES) { row_ptr[i0 + 1] = ex + v0; deg_cursor[i0 + 1] = ex + v0; }
    if (b == 0 && t == 0) row_ptr[N_NODES] = N_EDGES;
}

__global__ __launch_bounds__(256) void scatter_kernel(const int* __restrict__ rows,
                                                      const int* __restrict__ cols,
                                                      const float* __restrict__ w,
                                                      int* __restrict__ cursor,
                                                      int2* __restrict__ csr) {
    int e = blockIdx.x * 256 + threadIdx.x;
    if (e < N_EDGES) {
        int pos = atomicAdd(&cursor[rows[e]], 1);
        int2 cw;
        cw.x = cols[e];
        cw.y = __float_as_int((1.0f - ALPHA) * w[e]);  // fold 0.9 into the weight
        csr[pos] = cw;
    }
}

// x fp32 -> packed 2xbf16 per u32 (row-major, 64 u32 per row)
__global__ __launch_bounds__(256) void x_to_bf16(const float2* __restrict__ x2,
                                                 unsigned* __restrict__ xb, int n) {
    int i = blockIdx.x * 256 + threadIdx.x;
    if (i < n) {
        float2 v = x2[i];
        xb[i] = f2bf(v.x) | (f2bf(v.y) << 16);
    }
}

// ---------- tier-1 propagation: 16 edges/iter, 4 gathers in flight ----------
// Lane l = (sub = l>>4, fl = l&15). Per iter, lane handles csr[j+4q+sub] for
// q=0..3 (own col+w) and gathers 16B (8 bf16 feats) per sub-edge. Masked tail
// slots gather col 0 (L2-hot). Epilogue: shfl_xor(16,32); sub==0 stores.

template <bool DST_BF, bool X_BF>
__global__ __launch_bounds__(256) void row_spmm_q(const int* __restrict__ rp,
                                                  const int2* __restrict__ csr,
                                                  const void* __restrict__ xsrc,
                                                  const unsigned* __restrict__ src,
                                                  void* __restrict__ dst) {
    int row = (blockIdx.x * 256 + threadIdx.x) >> 6;
    int lane = threadIdx.x & 63;
    if (row >= N_NODES) return;
    int cn = rp[row];
    cn = (cn < MAXDEG) ? cn : MAXDEG;
    const int beg = row << 6;
    const int end = beg + cn;
    const int sub = lane >> 4;
    const int fl  = lane & 15;

    // x-term slice for this lane's 8 features: issued early, used at epilogue.
    uint4 xu; float4 xa, xc;
    if (X_BF) {
        xu = ((const uint4*)xsrc)[(size_t)row * 16 + fl];
    } else {
        xa = ((const float4*)xsrc)[(size_t)row * 32 + 2 * fl];
        xc = ((const float4*)xsrc)[(size_t)row * 32 + 2 * fl + 1];
    }

    const uint4* s4 = (const uint4*)src;  // row = 16 uint4; slice fl

    float acc[8];
    #pragma unroll
    for (int k = 0; k < 8; ++k) acc[k] = 0.f;

    for (int j = beg; j < end; j += 16) {
        int idx[4]; bool vv[4]; int2 cc[4];
        #pragma unroll
        for (int q = 0; q < 4; ++q) {
            idx[q] = j + 4 * q + sub;
            vv[q] = idx[q] < end;
            cc[q] = csr[idx[q]];  // <=152B past last row's window; csrp slack
        }
        int   col[4]; float ww[4];
        #pragma unroll
        for (int q = 0; q < 4; ++q) {
            col[q] = vv[q] ? cc[q].x : 0;
            ww[q]  = vv[q] ? __int_as_float(cc[q].y) : 0.f;
        }
        uint4 g[4];
        #pragma unroll
        for (int q = 0; q < 4; ++q) g[q] = s4[(size_t)col[q] * 16 + fl];
        #pragma unroll
        for (int q = 0; q < 4; ++q) {
            float wq = ww[q];
            acc[0] += wq * bflo(g[q].x);
            acc[1] += wq * bfhi(g[q].x);
            acc[2] += wq * bflo(g[q].y);
            acc[3] += wq * bfhi(g[q].y);
            acc[4] += wq * bflo(g[q].z);
            acc[5] += wq * bfhi(g[q].z);
            acc[6] += wq * bflo(g[q].w);
            acc[7] += wq * bfhi(g[q].w);
        }
    }

    // Sum the 4 sub-groups (lanes fl, fl+16, fl+32, fl+48 share features).
    #pragma unroll
    for (int k = 0; k < 8; ++k) {
        acc[k] += __shfl_xor(acc[k], 16);
        acc[k] += __shfl_xor(acc[k], 32);
    }

    // alpha * x   (note: bfhi gives the feature value directly; low needs <<16)
    if (X_BF) {
        acc[0] += ALPHA * bflo(xu.x);
        acc[1] += ALPHA * bfhi(xu.x);
        acc[2] += ALPHA * bflo(xu.y);
        acc[3] += ALPHA * bfhi(xu.y);
        acc[4] += ALPHA * bflo(xu.z);
        acc[5] += ALPHA * bfhi(xu.z);
        acc[6] += ALPHA * bflo(xu.w);
        acc[7] += ALPHA * bfhi(xu.w);
    } else {
        acc[0] += ALPHA * xa.x; acc[1] += ALPHA * xa.y;
        acc[2] += ALPHA * xa.z; acc[3] += ALPHA * xa.w;
        acc[4] += ALPHA * xc.x; acc[5] += ALPHA * xc.y;
        acc[6] += ALPHA * xc.z; acc[7] += ALPHA * xc.w;
    }

    if (DST_BF) {
        if (sub == 0) {
            uint4 o;
            o.x = f2bf(acc[0]) | (f2bf(acc[1]) << 16);
            o.y = f2bf(acc[2]) | (f2bf(acc[3]) << 16);
            o.z = f2bf(acc[4]) | (f2bf(acc[5]) << 16);
            o.w = f2bf(acc[6]) | (f2bf(acc[7]) << 16);
            ((uint4*)dst)[(size_t)row * 16 + fl] = o;
        }
    } else {
        if (sub == 0) {
            float4 o; o.x = acc[0]; o.y = acc[1]; o.z = acc[2]; o.w = acc[3];
            ((float4*)dst)[(size_t)row * 32 + 2 * fl] = o;
        } else if (sub == 1) {
            float4 o; o.x = acc[4]; o.y = acc[5]; o.z = acc[6]; o.w = acc[7];
            ((float4*)dst)[(size_t)row * 32 + 2 * fl + 1] = o;
        }
    }
}

// ---------- propagation (fallback tiers, R8-exact) ----------

template <bool SRC_BF, bool DST_BF, bool X_BF, bool PAD>
__global__ __launch_bounds__(256) void row_spmm_t(const int* __restrict__ rp,
                                                  const int2* __restrict__ csr,
                                                  const void* __restrict__ xsrc,
                                                  const void* __restrict__ src,
                                                  void* __restrict__ dst) {
    int row = (blockIdx.x * 256 + threadIdx.x) >> 6;
    int lane = threadIdx.x & 63;
    if (row >= N_NODES) return;
    int beg, end;
    if (PAD) {
        int cn = rp[row];
        cn = (cn < MAXDEG) ? cn : MAXDEG;
        beg = row << 6;
        end = beg + cn;
    } else {
        beg = rp[row];
        end = rp[row + 1];
    }

    float xtx, xty;
    if (X_BF) {
        unsigned u = ((const unsigned*)xsrc)[(size_t)row * 64 + lane];
        xtx = ALPHA * bf2f(u & 0xffffu);
        xty = ALPHA * bf2f(u >> 16);
    } else {
        float2 xv = ((const float2*)xsrc)[(size_t)row * 64 + lane];
        xtx = ALPHA * xv.x;
        xty = ALPHA * xv.y;
    }

    const float2*   sf = (const float2*)src;
    const unsigned* sb = (const unsigned*)src;

    float ax[4] = {0.f, 0.f, 0.f, 0.f};
    float ay[4] = {0.f, 0.f, 0.f, 0.f};

    auto gather = [&](int col) -> float2 {
        if (SRC_BF) {
            unsigned u = sb[(size_t)col * 64 + lane];
            float2 v;
            v.x = bf2f(u & 0xffffu);
            v.y = bf2f(u >> 16);
            return v;
        } else {
            return sf[(size_t)col * 64 + lane];
        }
    };

    int j = beg;
    while (j + 8 <= end) {
        int2 cw[8];
        #pragma unroll
        for (int u = 0; u < 8; ++u) cw[u] = csr[j + u];
        float2 v[8];
        #pragma unroll
        for (int u = 0; u < 8; ++u) v[u] = gather(cw[u].x);
        #pragma unroll
        for (int u = 0; u < 8; ++u) {
            float wv = __int_as_float(cw[u].y);
            ax[u & 3] += wv * v[u].x;
            ay[u & 3] += wv * v[u].y;
        }
        j += 8;
    }
    while (j + 4 <= end) {
        int2 cw[4];
        #pragma unroll
        for (int u = 0; u < 4; ++u) cw[u] = csr[j + u];
        float2 v[4];
        #pragma unroll
        for (int u = 0; u < 4; ++u) v[u] = gather(cw[u].x);
        #pragma unroll
        for (int u = 0; u < 4; ++u) {
            float wv = __int_as_float(cw[u].y);
            ax[u] += wv * v[u].x;
            ay[u] += wv * v[u].y;
        }
        j += 4;
    }
    for (; j < end; ++j) {
        int2 cw = csr[j];
        float2 v = gather(cw.x);
        float wv = __int_as_float(cw.y);
        ax[0] += wv * v.x;
        ay[0] += wv * v.y;
    }

    float ox = xtx + (ax[0] + ax[1]) + (ax[2] + ax[3]);
    float oy = xty + (ay[0] + ay[1]) + (ay[2] + ay[3]);

    if (DST_BF) {
        ((unsigned*)dst)[(size_t)row * 64 + lane] = f2bf(ox) | (f2bf(oy) << 16);
    } else {
        float2 o; o.x = ox; o.y = oy;
        ((float2*)dst)[(size_t)row * 64 + lane] = o;
    }
}

// ---------- fallback (R0 atomic path) if ws too small ----------

__global__ __launch_bounds__(256) void init_step(const float4* __restrict__ x,
                                                 float4* __restrict__ dst, int n4) {
    int i = blockIdx.x * 256 + threadIdx.x;
    if (i < n4) {
        float4 v = x[i];
        dst[i] = make_float4(ALPHA * v.x, ALPHA * v.y, ALPHA * v.z, ALPHA * v.w);
    }
}

__global__ __launch_bounds__(256) void edge_scatter(const int* __restrict__ rows,
                                                    const int* __restrict__ cols,
                                                    const float* __restrict__ w,
                                                    const float* __restrict__ h,
                                                    float* __restrict__ dst) {
    unsigned t = blockIdx.x * 256u + threadIdx.x;
    unsigned e = t >> 5;
    unsigned l = t & 31u;
    if (e >= N_EDGES) return;
    int r = rows[e];
    int c = cols[e];
    float we = (1.0f - ALPHA) * w[e];
    const float4* hc = (const float4*)(h + (size_t)c * D_FEAT);
    float4 v = hc[l];
    float* dr = dst + (size_t)r * D_FEAT + (size_t)l * 4;
    unsafeAtomicAdd(dr + 0, we * v.x);
    unsafeAtomicAdd(dr + 1, we * v.y);
    unsafeAtomicAdd(dr + 2, we * v.z);
    unsafeAtomicAdd(dr + 3, we * v.w);
}

extern "C" void kernel_launch(void* const* d_in, const int* in_sizes, int n_in,
                              void* d_out, int out_size, void* d_ws, size_t ws_size,
                              hipStream_t stream) {
    const float* x  = (const float*)d_in[0];
    const int*   ei = (const int*)d_in[1];  // [2, E] flat: rows then cols
    const float* ev = (const float*)d_in[2];
    const int* rows = ei;
    const int* cols = ei + N_EDGES;
    float* out = (float*)d_out;

    auto align512 = [](size_t o) { return (o + 511) & ~(size_t)511; };

    // --- padded layout (tier 1), 512B-aligned: ha, hb, xb, cnt+gcount, csrp.
    // gbuf (pass-A bucket buffer, 50.2 MB) aliases contiguous [hb, xb).
    // csrp gets +512B slack for the masked tail over-read in row_spmm_q.
    size_t p_off = 0;
    size_t p_ha   = p_off; p_off = align512(p_off + (size_t)N_NODES * D_FEAT * 2);
    size_t p_hb   = p_off; p_off = align512(p_off + (size_t)N_NODES * D_FEAT * 2);
    size_t p_xb   = p_off; p_off = align512(p_off + (size_t)N_NODES * D_FEAT * 2);
    size_t p_cnt  = p_off; p_off = align512(p_off + (size_t)N_NODES * 4 + NBUCK * 4);
    size_t p_csr  = p_off; p_off = align512(p_off + (size_t)N_NODES * MAXDEG * 8 + 512);
    size_t need_pad = p_off;  // ~128.6 MB
    static_assert((size_t)NBUCK * BCAP * 16 <= 2 * (size_t)N_NODES * D_FEAT * 2,
                  "gbuf must fit in hb+xb");

    // --- compact layout (tiers 2/3): ha, hb, rowptr, cursor, partial, csr, [xb] ---
    size_t c_off = 0;
    size_t c_ha      = c_off; c_off = align512(c_off + (size_t)N_NODES * D_FEAT * 2);
    size_t c_hb      = c_off; c_off = align512(c_off + (size_t)N_NODES * D_FEAT * 2);
    size_t c_rowptr  = c_off; c_off = align512(c_off + (size_t)(N_NODES + 1) * 4);
    size_t c_cursor  = c_off; c_off = align512(c_off + (size_t)N_NODES * 4);
    size_t c_partial = c_off; c_off = align512(c_off + (size_t)SCAN_NBLK * 4);
    size_t c_csr     = c_off; c_off = align512(c_off + (size_t)N_EDGES * 8);
    size_t need_base = c_off;  // ~64.8 MB
    size_t c_xb      = c_off; c_off = align512(c_off + (size_t)N_NODES * D_FEAT * 2);
    size_t need_xb   = c_off;  // ~90.4 MB

    const int row_blocks = (N_NODES * 64 + 255) / 256;  // 25000 (1 wave/row)
    const float2* x2 = (const float2*)x;

    if (ws_size >= need_pad) {
        // ---- tier 1: bucketed padded CSR build + 16-edge spmm ----
        char* ws = (char*)d_ws;
        void*     h_a    = (void*)(ws + p_ha);
        void*     h_b    = (void*)(ws + p_hb);
        unsigned* xb     = (unsigned*)(ws + p_xb);
        int*      cnt    = (int*)(ws + p_cnt);
        int*      gcount = cnt + N_NODES;
        int2*     csrp   = (int2*)(ws + p_csr);
        int4*     gbuf   = (int4*)(ws + p_hb);  // aliases hb+xb during build

        hipMemsetAsync(cnt, 0, (size_t)N_NODES * 4 + NBUCK * 4, stream);
        const int blocks_a = (N_EDGES + EPB_A - 1) / EPB_A;  // 782
        bucket_scatter<<<blocks_a, 256, 0, stream>>>(rows, cols, ev, gcount, gbuf);
        bucket_to_csr<<<NBUCK, 256, 0, stream>>>(gcount, gbuf, cnt, csrp);

        const int nxb = N_NODES * D_FEAT / 2;
        x_to_bf16<<<(nxb + 255) / 256, 256, 0, stream>>>(x2, xb, nxb);

        row_spmm_q<true, true><<<row_blocks, 256, 0, stream>>>(
            cnt, csrp, (const void*)xb, xb, h_a);
        for (int k = 1; k <= 8; ++k) {
            const void* src = (k & 1) ? h_a : h_b;
            void* dst = (k & 1) ? h_b : h_a;
            row_spmm_q<true, true><<<row_blocks, 256, 0, stream>>>(
                cnt, csrp, (const void*)xb, (const unsigned*)src, dst);
        }
        row_spmm_q<false, false><<<row_blocks, 256, 0, stream>>>(
            cnt, csrp, (const void*)x2, (const unsigned*)h_a, (void*)out);
    } else if (ws_size >= need_base) {
        // ---- tiers 2/3: compact CSR (R5 path) ----
        char* ws = (char*)d_ws;
        void*  h_a     = (void*)(ws + c_ha);
        void*  h_b     = (void*)(ws + c_hb);
        int*   row_ptr = (int*)(ws + c_rowptr);
        int*   cursor  = (int*)(ws + c_cursor);
        int*   partial = (int*)(ws + c_partial);
        int2*  csr     = (int2*)(ws + c_csr);
        unsigned* xb   = (unsigned*)(ws + c_xb);
        const bool has_xb = (ws_size >= need_xb);
        const int edge_blocks_1t = (N_EDGES + 255) / 256;  // 6250

        hipMemsetAsync(cursor, 0, (size_t)N_NODES * 4, stream);
        hist_kernel<<<edge_blocks_1t, 256, 0, stream>>>(rows, cursor);
        scan_partial<<<SCAN_NBLK, 256, 0, stream>>>(cursor, partial);
        scan_top<<<1, 256, 0, stream>>>(partial);
        scan_final<<<SCAN_NBLK, 256, 0, stream>>>(cursor, partial, row_ptr);
        scatter_kernel<<<edge_blocks_1t, 256, 0, stream>>>(rows, cols, ev, cursor, csr);

        if (has_xb) {
            const int nxb = N_NODES * D_FEAT / 2;
            x_to_bf16<<<(nxb + 255) / 256, 256, 0, stream>>>(x2, xb, nxb);
            row_spmm_t<true, true, true, false><<<row_blocks, 256, 0, stream>>>(
                row_ptr, csr, (const void*)xb, (const void*)xb, h_a);
            for (int k = 1; k <= 8; ++k) {
                const void* src = (k & 1) ? h_a : h_b;
                void* dst = (k & 1) ? h_b : h_a;
                row_spmm_t<true, true, true, false><<<row_blocks, 256, 0, stream>>>(
                    row_ptr, csr, (const void*)xb, src, dst);
            }
            row_spmm_t<true, false, false, false><<<row_blocks, 256, 0, stream>>>(
                row_ptr, csr, (const void*)x2, (const void*)h_a, (void*)out);
        } else {
            row_spmm_t<false, true, false, false><<<row_blocks, 256, 0, stream>>>(
                row_ptr, csr, (const void*)x2, (const void*)x, h_a);
            for (int k = 1; k <= 8; ++k) {
                const void* src = (k & 1) ? h_a : h_b;
                void* dst = (k & 1) ? h_b : h_a;
                row_spmm_t<true, true, false, false><<<row_blocks, 256, 0, stream>>>(
                    row_ptr, csr, (const void*)x2, src, dst);
            }
            row_spmm_t<true, false, false, false><<<row_blocks, 256, 0, stream>>>(
                row_ptr, csr, (const void*)x2, (const void*)h_a, (void*)out);
        }
    } else {
        // Fallback: R0 atomic path (needs only the 51.2 MB ping buffer)
        float* wsf = (float*)d_ws;
        const int n4 = N_NODES * D_FEAT / 4;
        const int init_blocks = (n4 + 255) / 256;
        const int edge_blocks = (N_EDGES * 32 + 255) / 256;
        for (int k = 0; k < K_STEPS; ++k) {
            const float* src = (k == 0) ? x : ((k & 1) ? wsf : out);
            float* dst = (k & 1) ? out : wsf;
            init_step<<<init_blocks, 256, 0, stream>>>((const float4*)x, (float4*)dst, n4);
            edge_scatter<<<edge_blocks, 256, 0, stream>>>(rows, cols, ev, src, dst);
        }
    }
}